// Round 4
// baseline (121.838 us; speedup 1.0000x reference)
//
#include <hip/hip_runtime.h>
#include <math.h>

#define HH 1024
#define WW 1024
#define CD 900
#define MS 10
#define CS 62            // (H-CD)/2
#define OFFT 72          // MS+CS
#define TW 880           // H-2*OFF
#define SS 21            // 2*MS+1
#define EPSV 1e-8
#define NBAND 55         // 880/16 bands of template rows
#define RPB 16           // template rows per corr block
#define NCH 55           // 880/16 column chunks of 16
#define NPAIR 441        // 21*21
#define NIG 7            // i-groups (3 lags each): 21 = 3*7
#define IPG 3            // i per group
#define AROWS 18         // RPB + IPG - 1 X-rows touched per (band, group)
#define NCORR (NBAND * NIG)  // 385 corr blocks

// ws layout (floats):
//   RS1T  : w + 0        [21*900]  window sums, transposed [j][row]
//   RS2T  : w + 75600    [21*900]
//   Trow1 : w + 151200   [880]
//   Trow2 : w + 154720   [880]
//   Sfull : w + 158240   [900]
//   part  : w + 161840   [21*55*21]

// ---------------- fused: raw cross-correlation (3-i blocked) + row statistics ----
// blocks [0, 385): corr — 16 template rows vs 3 row-lags; X row loaded once, used
//   for 3 (lag, template-row) pairs -> L2 traffic /3 vs 1-i blocking.
// blocks [385, 385+1780): per-row window sums / template row sums.
__global__ __launch_bounds__(256) void fused_corr_stats(const float* __restrict__ X,
                                                        const float* __restrict__ T,
                                                        float* __restrict__ RS1T,
                                                        float* __restrict__ RS2T,
                                                        float* __restrict__ Trow1,
                                                        float* __restrict__ Trow2,
                                                        float* __restrict__ Sfull,
                                                        float* __restrict__ part) {
    const int bx = blockIdx.x;
    const int tid = threadIdx.x;
    const int lane = tid & 63, wid = tid >> 6;
    __shared__ float red[4][IPG * SS];

    if (bx < NCORR) {
        // ---- corr: block = (band of 16 template rows, group of 3 lags) ----
        const int g = bx / NBAND;
        const int band = bx - g * NBAND;
        const int i0 = g * IPG;
        const int u0 = band * RPB;

        float acc[IPG][SS];
#pragma unroll
        for (int d = 0; d < IPG; ++d)
#pragma unroll
            for (int j = 0; j < SS; ++j) acc[d][j] = 0.f;

        // item = (a, c): X row CS+i0+u0+a, 16-col chunk c.
        // For d=0..2: template row u = a-d (valid if 0<=u<16); lag i0+d.
#pragma unroll 1
        for (int item = tid; item < AROWS * NCH; item += 256) {
            const int a = item / NCH;
            const int c = item - a * NCH;
            // x cols [60+16c, 100+16c): 16B-aligned; needed cols 62+16c+j+k (j+k<=35)
            const float4* xp = (const float4*)(X + (size_t)(CS + i0 + u0 + a) * WW + 60 + c * 16);
            float xr[40];
#pragma unroll
            for (int k = 0; k < 10; ++k) {
                float4 q = xp[k];
                xr[4 * k] = q.x; xr[4 * k + 1] = q.y; xr[4 * k + 2] = q.z; xr[4 * k + 3] = q.w;
            }
#pragma unroll
            for (int d = 0; d < IPG; ++d) {
                const int u = a - d;
                if (u >= 0 && u < RPB) {
                    // t cols [72+16c, 88+16c): 16B-aligned
                    const float4* tp = (const float4*)(T + (size_t)(OFFT + u0 + u) * WW + OFFT + c * 16);
                    float t[16];
#pragma unroll
                    for (int k = 0; k < 4; ++k) {
                        float4 q = tp[k];
                        t[4 * k] = q.x; t[4 * k + 1] = q.y; t[4 * k + 2] = q.z; t[4 * k + 3] = q.w;
                    }
#pragma unroll
                    for (int j = 0; j < SS; ++j) {
                        float s = acc[d][j];
#pragma unroll
                        for (int k = 0; k < 16; ++k) s = fmaf(xr[2 + j + k], t[k], s);
                        acc[d][j] = s;
                    }
                }
            }
        }

#pragma unroll
        for (int d = 0; d < IPG; ++d)
#pragma unroll
            for (int j = 0; j < SS; ++j)
#pragma unroll
                for (int m = 1; m < 64; m <<= 1) acc[d][j] += __shfl_xor(acc[d][j], m);

        if (lane == 0) {
#pragma unroll
            for (int d = 0; d < IPG; ++d)
#pragma unroll
                for (int j = 0; j < SS; ++j) red[wid][d * SS + j] = acc[d][j];
        }
        __syncthreads();
        if (tid < IPG * SS) {
            const int d = tid / SS, j = tid - d * SS;
            float s = red[0][tid] + red[1][tid] + red[2][tid] + red[3][tid];
            part[((i0 + d) * NBAND + band) * SS + j] = s;
        }
    } else {
        // ---- row statistics part (no atomics, no memset needed) ----
        const int b = bx - NCORR;
        if (b < CD) {
            const float* row = X + (size_t)(CS + b) * WW + CS;   // 900 valid cols
            float sf = 0.f, sw = 0.f, qw = 0.f;
            for (int v = tid; v < CD; v += 256) {
                float x = row[v];
                sf += x;
                if (v < TW) { sw += x; qw += x * x; }
            }
            for (int m = 1; m < 64; m <<= 1) {
                sf += __shfl_xor(sf, m); sw += __shfl_xor(sw, m); qw += __shfl_xor(qw, m);
            }
            if (lane == 0) { red[wid][0] = sf; red[wid][1] = sw; red[wid][2] = qw; }
            __syncthreads();
            if (tid < 32) {
                const float swb = red[0][1] + red[1][1] + red[2][1] + red[3][1];
                const float qwb = red[0][2] + red[1][2] + red[2][2] + red[3][2];
                // lag-j window sum = base + prefix sum of slide deltas (parallel scan)
                float d1 = 0.f, d2 = 0.f;
                if (tid >= 1 && tid < SS) {
                    float a = row[tid - 1], c2 = row[TW + tid - 1];
                    d1 = c2 - a;
                    d2 = c2 * c2 - a * a;
                }
                for (int off = 1; off < 32; off <<= 1) {
                    float u1 = __shfl_up(d1, off), u2 = __shfl_up(d2, off);
                    if (tid >= off) { d1 += u1; d2 += u2; }
                }
                if (tid < SS) {
                    RS1T[tid * CD + b] = swb + d1;
                    RS2T[tid * CD + b] = qwb + d2;
                }
                if (tid == 0) Sfull[b] = red[0][0] + red[1][0] + red[2][0] + red[3][0];
            }
        } else {
            const int u = b - CD;
            const float* row = T + (size_t)(OFFT + u) * WW + OFFT;
            float s = 0.f, q = 0.f;
            for (int v = tid; v < TW; v += 256) { float t = row[v]; s += t; q += t * t; }
            for (int m = 1; m < 64; m <<= 1) { s += __shfl_xor(s, m); q += __shfl_xor(q, m); }
            if (lane == 0) { red[wid][0] = s; red[wid][1] = q; }
            __syncthreads();
            if (tid == 0) {
                Trow1[u] = red[0][0] + red[1][0] + red[2][0] + red[3][0];
                Trow2[u] = red[0][1] + red[1][1] + red[2][1] + red[3][1];
            }
        }
    }
}

// ---------------- merged ncc + shift: each block redundantly computes ncc[441] ---
// Phase A (identical fp sequence in every block -> bit-identical -> same argmax):
//   sliding-window over i: S(i,j) = S(i-1,j) + RS[j][i+879] - RS[j][i-1].
// Phase B: bilinear sample + transposed store.
__global__ __launch_bounds__(256) void ncc_shift_kernel(const float* __restrict__ img,
                                                        const float* __restrict__ part,
                                                        const float* __restrict__ RS1T,
                                                        const float* __restrict__ RS2T,
                                                        const float* __restrict__ Trow1,
                                                        const float* __restrict__ Trow2,
                                                        const float* __restrict__ Sfull,
                                                        float* __restrict__ out) {
    const int tid = threadIdx.x, lane = tid & 63, wid = tid >> 6;
    __shared__ double sh_b1[SS], sh_b2[SS];
    __shared__ double sh_dot[NPAIR];
    __shared__ double sh_d1[420], sh_d2[420];
    __shared__ double sh_S1[NPAIR], sh_S2[NPAIR];
    __shared__ double redsc[4][3];
    __shared__ double sh_scal[3];
    __shared__ float nccs[NPAIR];
    __shared__ float sv[256];
    __shared__ int si[256];
    __shared__ float sxy[2];
    __shared__ float tile[64][65];

    // ---- phase A: base window sums (wave w handles j = w, w+4, ...) ----
    for (int j = wid; j < SS; j += 4) {
        const float* r1 = RS1T + j * CD;
        const float* r2 = RS2T + j * CD;
        double s1 = 0, s2 = 0;
        for (int u = lane; u < TW; u += 64) { s1 += (double)r1[u]; s2 += (double)r2[u]; }
        for (int m = 1; m < 64; m <<= 1) { s1 += __shfl_xor(s1, m); s2 += __shfl_xor(s2, m); }
        if (lane == 0) { sh_b1[j] = s1; sh_b2[j] = s2; }
    }
    // scalars (template sums, image sum)
    {
        double ta = 0, tb = 0, xsum = 0;
        for (int u = tid; u < TW; u += 256) { ta += (double)Trow1[u]; tb += (double)Trow2[u]; }
        for (int k = tid; k < CD; k += 256) xsum += (double)Sfull[k];
        for (int m = 1; m < 64; m <<= 1) {
            ta += __shfl_xor(ta, m); tb += __shfl_xor(tb, m); xsum += __shfl_xor(xsum, m);
        }
        if (lane == 0) { redsc[wid][0] = ta; redsc[wid][1] = tb; redsc[wid][2] = xsum; }
    }
    // band-partial dots
    for (int p = tid; p < NPAIR; p += 256) {
        const int i = p / SS, j = p - i * SS;
        double dv = 0;
        for (int b = 0; b < NBAND; ++b) dv += (double)part[(i * NBAND + b) * SS + j];
        sh_dot[p] = dv;
    }
    // slide deltas
    for (int q = tid; q < 420; q += 256) {
        const int ii = q / SS + 1;              // 1..20
        const int j = q - (ii - 1) * SS;
        sh_d1[q] = (double)RS1T[j * CD + ii + 879] - (double)RS1T[j * CD + ii - 1];
        sh_d2[q] = (double)RS2T[j * CD + ii + 879] - (double)RS2T[j * CD + ii - 1];
    }
    __syncthreads();

    // sliding scan over i (threads 0..20); scalar combine (threads 32..34)
    if (tid < SS) {
        const int j = tid;
        double w1 = sh_b1[j], w2 = sh_b2[j];
        sh_S1[j] = w1; sh_S2[j] = w2;
        for (int i2 = 1; i2 < SS; ++i2) {
            w1 += sh_d1[(i2 - 1) * SS + j];
            w2 += sh_d2[(i2 - 1) * SS + j];
            sh_S1[i2 * SS + j] = w1;
            sh_S2[i2 * SS + j] = w2;
        }
    } else if (tid >= 32 && tid < 35) {
        const int s = tid - 32;
        sh_scal[s] = redsc[0][s] + redsc[1][s] + redsc[2][s] + redsc[3][s];
    }
    __syncthreads();

    // ncc values + per-thread argmax (increasing p -> first-occurrence kept on ties)
    {
        float best = -1e30f; int bi = 0;
        const double NT = 774400.0;
        const double sum_t = sh_scal[0], sum_t2 = sh_scal[1], sumX = sh_scal[2];
        const double mt = sum_t / NT, mx = sumX / 810000.0;
        const double tvar = sum_t2 - sum_t * sum_t / NT + EPSV;
        for (int p = tid; p < NPAIR; p += 256) {
            const double dot = sh_dot[p], S1 = sh_S1[p], S2 = sh_S2[p];
            double var = S2 - S1 * S1 / NT + EPSV;
            if (var < 0.0) var = 0.0;
            const double cross = dot - mt * S1 - mx * sum_t + NT * mx * mt;
            float v = (float)(cross / sqrt(tvar * var));
            if (isnan(v)) v = 0.f;
            nccs[p] = v;
            if (v > best) { best = v; bi = p; }
        }
        sv[tid] = best; si[tid] = bi;
    }
    __syncthreads();
    for (int off = 128; off > 0; off >>= 1) {
        if (tid < off) {
            float v2 = sv[tid + off]; int i2 = si[tid + off];
            if (v2 > sv[tid] || (v2 == sv[tid] && i2 < si[tid])) { sv[tid] = v2; si[tid] = i2; }
        }
        __syncthreads();
    }
    if (tid == 0) {
        const int idx = si[0];
        const int sx = idx / SS;
        const int sy = idx - sx * SS;
        auto at = [&](int r, int c) -> float {
            r = r < 0 ? 0 : (r > SS - 1 ? SS - 1 : r);
            c = c < 0 ? 0 : (c > SS - 1 ? SS - 1 : c);
            return logf(nccs[r * SS + c]);
        };
        const float l4 = 4.0f * at(sx, sy);
        const float lxm = at(sx - 1, sy), lxp = at(sx + 1, sy);
        const float lym = at(sx, sy - 1), lyp = at(sx, sy + 1);
        const float xsv = -((float)sx - (float)MS) - (lxm - lxp) / (2.0f * lxm - l4 + 2.0f * lxp);
        const float ysv = -((float)sy - (float)MS) - (lym - lyp) / (2.0f * lym - l4 + 2.0f * lyp);
        sxy[0] = xsv; sxy[1] = ysv;
        if (blockIdx.x == 0 && blockIdx.y == 0) {
            out[(size_t)HH * WW] = xsv;
            out[(size_t)HH * WW + 1] = ysv;
        }
    }
    __syncthreads();

    // ---- phase B: bilinear shift + transposed store ----
    const float xs = sxy[0], ys = sxy[1];
    const int R0 = blockIdx.y * 64, C0 = blockIdx.x * 64;
    {
        const int cl = tid & 63, rg = tid >> 6;
        const int c = C0 + cl;
        const float cc = (float)c - ys;
        const float c0f = floorf(cc);
        const float wc = cc - c0f;
        const int c0 = (int)c0f;
        const bool vc0 = (c0 >= 0) & (c0 < WW);
        const bool vc1 = (c0 + 1 >= 0) & (c0 + 1 < WW);
        const int c0c = c0 < 0 ? 0 : (c0 > WW - 1 ? WW - 1 : c0);
        const int c1c = (c0 + 1) < 0 ? 0 : ((c0 + 1) > WW - 1 ? WW - 1 : c0 + 1);
        for (int k = 0; k < 16; ++k) {
            const int rl = rg * 16 + k;
            const int r = R0 + rl;
            const float rr = (float)r - xs;
            const float r0f = floorf(rr);
            const float wr = rr - r0f;
            const int r0 = (int)r0f;
            const bool vr0 = (r0 >= 0) & (r0 < HH);
            const bool vr1 = (r0 + 1 >= 0) & (r0 + 1 < HH);
            const int r0c = r0 < 0 ? 0 : (r0 > HH - 1 ? HH - 1 : r0);
            const int r1c = (r0 + 1) < 0 ? 0 : ((r0 + 1) > HH - 1 ? HH - 1 : r0 + 1);
            float s00 = img[(size_t)r0c * WW + c0c]; if (!(vr0 & vc0)) s00 = 0.f;
            float s01 = img[(size_t)r0c * WW + c1c]; if (!(vr0 & vc1)) s01 = 0.f;
            float s10 = img[(size_t)r1c * WW + c0c]; if (!(vr1 & vc0)) s10 = 0.f;
            float s11 = img[(size_t)r1c * WW + c1c]; if (!(vr1 & vc1)) s11 = 0.f;
            tile[rl][cl] = (1.f - wr) * (1.f - wc) * s00 + (1.f - wr) * wc * s01 +
                           wr * (1.f - wc) * s10 + wr * wc * s11;
        }
    }
    __syncthreads();
    {
        const int rl = tid & 63, cg = tid >> 6;
        for (int k = 0; k < 16; ++k) {
            const int cl = cg * 16 + k;
            out[(size_t)(C0 + cl) * HH + R0 + rl] = tile[rl][cl];
        }
    }
}

extern "C" void kernel_launch(void* const* d_in, const int* in_sizes, int n_in,
                              void* d_out, int out_size, void* d_ws, size_t ws_size,
                              hipStream_t stream) {
    const float* X = (const float*)d_in[0];
    const float* T = (const float*)d_in[1];
    float* out = (float*)d_out;

    char* w = (char*)d_ws;
    float* RS1T  = (float*)(w + 0);
    float* RS2T  = (float*)(w + 75600);
    float* Trow1 = (float*)(w + 151200);
    float* Trow2 = (float*)(w + 154720);
    float* Sfull = (float*)(w + 158240);
    float* part  = (float*)(w + 161840);

    fused_corr_stats<<<NCORR + CD + TW, 256, 0, stream>>>(X, T, RS1T, RS2T, Trow1, Trow2, Sfull, part);
    ncc_shift_kernel<<<dim3(16, 16), 256, 0, stream>>>(X, part, RS1T, RS2T, Trow1, Trow2, Sfull, out);
}

// Round 5
// 99.887 us; speedup vs baseline: 1.2198x; 1.2198x over previous
//
#include <hip/hip_runtime.h>
#include <math.h>

#define HH 1024
#define WW 1024
#define CD 900
#define MS 10
#define CS 62            // (H-CD)/2
#define OFFT 72          // MS+CS
#define TW 880           // H-2*OFF
#define SS 21            // 2*MS+1
#define EPSV 1e-8
#define NBAND 55         // 880/16 bands of template rows
#define RPB 16           // template rows per corr block
#define NCH 55           // 880/16 column chunks of 16
#define NPAIR 441        // 21*21
#define NIG 7            // i-groups (3 lags each): 21 = 3*7
#define IPG 3            // i per group
#define AROWS 18         // RPB + IPG - 1 X-rows touched per (band, group)
#define NCORR (NBAND * NIG)  // 385 corr blocks

// ws layout (floats):
//   RS1T  : w + 0        [21*900]  window sums, transposed [j][row]
//   RS2T  : w + 75600    [21*900]
//   Trow1 : w + 151200   [880]
//   Trow2 : w + 154720   [880]
//   Sfull : w + 158240   [900]
//   part  : w + 161840   [21*55*21]
//   ncc   : w + 258880   [441]

// ---------------- fused: raw cross-correlation (3-i blocked) + row statistics ----
// blocks [0, 385): corr — 16 template rows vs 3 row-lags; X row loaded once, used
//   for 3 (lag, template-row) pairs -> L2 traffic /3 vs 1-i blocking.
// blocks [385, 385+1780): per-row window sums / template row sums.
__global__ __launch_bounds__(256) void fused_corr_stats(const float* __restrict__ X,
                                                        const float* __restrict__ T,
                                                        float* __restrict__ RS1T,
                                                        float* __restrict__ RS2T,
                                                        float* __restrict__ Trow1,
                                                        float* __restrict__ Trow2,
                                                        float* __restrict__ Sfull,
                                                        float* __restrict__ part) {
    const int bx = blockIdx.x;
    const int tid = threadIdx.x;
    const int lane = tid & 63, wid = tid >> 6;
    __shared__ float red[4][IPG * SS];

    if (bx < NCORR) {
        // ---- corr: block = (band of 16 template rows, group of 3 lags) ----
        const int g = bx / NBAND;
        const int band = bx - g * NBAND;
        const int i0 = g * IPG;
        const int u0 = band * RPB;

        float acc[IPG][SS];
#pragma unroll
        for (int d = 0; d < IPG; ++d)
#pragma unroll
            for (int j = 0; j < SS; ++j) acc[d][j] = 0.f;

        // item = (a, c): X row CS+i0+u0+a, 16-col chunk c.
        // For d=0..2: template row u = a-d (valid if 0<=u<16); lag i0+d.
#pragma unroll 1
        for (int item = tid; item < AROWS * NCH; item += 256) {
            const int a = item / NCH;
            const int c = item - a * NCH;
            // x cols [60+16c, 100+16c): 16B-aligned; needed cols 62+16c+j+k (j+k<=35)
            const float4* xp = (const float4*)(X + (size_t)(CS + i0 + u0 + a) * WW + 60 + c * 16);
            float xr[40];
#pragma unroll
            for (int k = 0; k < 10; ++k) {
                float4 q = xp[k];
                xr[4 * k] = q.x; xr[4 * k + 1] = q.y; xr[4 * k + 2] = q.z; xr[4 * k + 3] = q.w;
            }
#pragma unroll
            for (int d = 0; d < IPG; ++d) {
                const int u = a - d;
                if (u >= 0 && u < RPB) {
                    // t cols [72+16c, 88+16c): 16B-aligned
                    const float4* tp = (const float4*)(T + (size_t)(OFFT + u0 + u) * WW + OFFT + c * 16);
                    float t[16];
#pragma unroll
                    for (int k = 0; k < 4; ++k) {
                        float4 q = tp[k];
                        t[4 * k] = q.x; t[4 * k + 1] = q.y; t[4 * k + 2] = q.z; t[4 * k + 3] = q.w;
                    }
#pragma unroll
                    for (int j = 0; j < SS; ++j) {
                        float s = acc[d][j];
#pragma unroll
                        for (int k = 0; k < 16; ++k) s = fmaf(xr[2 + j + k], t[k], s);
                        acc[d][j] = s;
                    }
                }
            }
        }

#pragma unroll
        for (int d = 0; d < IPG; ++d)
#pragma unroll
            for (int j = 0; j < SS; ++j)
#pragma unroll
                for (int m = 1; m < 64; m <<= 1) acc[d][j] += __shfl_xor(acc[d][j], m);

        if (lane == 0) {
#pragma unroll
            for (int d = 0; d < IPG; ++d)
#pragma unroll
                for (int j = 0; j < SS; ++j) red[wid][d * SS + j] = acc[d][j];
        }
        __syncthreads();
        if (tid < IPG * SS) {
            const int d = tid / SS, j = tid - d * SS;
            float s = red[0][tid] + red[1][tid] + red[2][tid] + red[3][tid];
            part[((i0 + d) * NBAND + band) * SS + j] = s;
        }
    } else {
        // ---- row statistics part (no atomics, no memset needed) ----
        const int b = bx - NCORR;
        if (b < CD) {
            const float* row = X + (size_t)(CS + b) * WW + CS;   // 900 valid cols
            float sf = 0.f, sw = 0.f, qw = 0.f;
            for (int v = tid; v < CD; v += 256) {
                float x = row[v];
                sf += x;
                if (v < TW) { sw += x; qw += x * x; }
            }
            for (int m = 1; m < 64; m <<= 1) {
                sf += __shfl_xor(sf, m); sw += __shfl_xor(sw, m); qw += __shfl_xor(qw, m);
            }
            if (lane == 0) { red[wid][0] = sf; red[wid][1] = sw; red[wid][2] = qw; }
            __syncthreads();
            if (tid < 32) {
                const float swb = red[0][1] + red[1][1] + red[2][1] + red[3][1];
                const float qwb = red[0][2] + red[1][2] + red[2][2] + red[3][2];
                // lag-j window sum = base + prefix sum of slide deltas (parallel scan)
                float d1 = 0.f, d2 = 0.f;
                if (tid >= 1 && tid < SS) {
                    float a = row[tid - 1], c2 = row[TW + tid - 1];
                    d1 = c2 - a;
                    d2 = c2 * c2 - a * a;
                }
                for (int off = 1; off < 32; off <<= 1) {
                    float u1 = __shfl_up(d1, off), u2 = __shfl_up(d2, off);
                    if (tid >= off) { d1 += u1; d2 += u2; }
                }
                if (tid < SS) {
                    RS1T[tid * CD + b] = swb + d1;
                    RS2T[tid * CD + b] = qwb + d2;
                }
                if (tid == 0) Sfull[b] = red[0][0] + red[1][0] + red[2][0] + red[3][0];
            }
        } else {
            const int u = b - CD;
            const float* row = T + (size_t)(OFFT + u) * WW + OFFT;
            float s = 0.f, q = 0.f;
            for (int v = tid; v < TW; v += 256) { float t = row[v]; s += t; q += t * t; }
            for (int m = 1; m < 64; m <<= 1) { s += __shfl_xor(s, m); q += __shfl_xor(q, m); }
            if (lane == 0) { red[wid][0] = s; red[wid][1] = q; }
            __syncthreads();
            if (tid == 0) {
                Trow1[u] = red[0][0] + red[1][0] + red[2][0] + red[3][0];
                Trow2[u] = red[0][1] + red[1][1] + red[2][1] + red[3][1];
            }
        }
    }
}

// ---------------- ncc via sliding scan: block j computes ncc[*, j] ----------------
// S(i,j) = S(0,j) + sum_{k<=i} (RS[j][k+879] - RS[j][k-1]); per-block loads ~3.6K
// (same order as the 441-block version's per-block count -> no latency cliff),
// total work 21x smaller.
__global__ __launch_bounds__(256) void ncc_scan_kernel(const float* __restrict__ part,
                                                       const float* __restrict__ RS1T,
                                                       const float* __restrict__ RS2T,
                                                       const float* __restrict__ Trow1,
                                                       const float* __restrict__ Trow2,
                                                       const float* __restrict__ Sfull,
                                                       float* __restrict__ ncc) {
    const int j = blockIdx.x;
    const int tid = threadIdx.x, lane = tid & 63, wid = tid >> 6;
    __shared__ double redb[4][5];
    __shared__ double sdot[SS];
    __shared__ double sd1[SS], sd2[SS];   // slide deltas, index i=1..20

    const float* r1 = RS1T + j * CD;
    const float* r2 = RS2T + j * CD;

    // base (i=0) window sums + scalar sums, 256-thread strided
    double s1 = 0, s2 = 0, ta = 0, tb = 0, xs = 0;
    for (int u = tid; u < TW; u += 256) {
        s1 += (double)r1[u]; s2 += (double)r2[u];
        ta += (double)Trow1[u]; tb += (double)Trow2[u];
    }
    for (int k = tid; k < CD; k += 256) xs += (double)Sfull[k];
    for (int m = 1; m < 64; m <<= 1) {
        s1 += __shfl_xor(s1, m); s2 += __shfl_xor(s2, m);
        ta += __shfl_xor(ta, m); tb += __shfl_xor(tb, m); xs += __shfl_xor(xs, m);
    }
    if (lane == 0) {
        redb[wid][0] = s1; redb[wid][1] = s2;
        redb[wid][2] = ta; redb[wid][3] = tb; redb[wid][4] = xs;
    }

    // band dots per i: wave w handles i = w, w+4, ...
    for (int i = wid; i < SS; i += 4) {
        double dv = 0;
        for (int b = lane; b < NBAND; b += 64) dv += (double)part[(i * NBAND + b) * SS + j];
        for (int m = 1; m < 64; m <<= 1) dv += __shfl_xor(dv, m);
        if (lane == 0) sdot[i] = dv;
    }

    // slide deltas i=1..20
    if (tid >= 1 && tid < SS) {
        sd1[tid] = (double)r1[tid + 879] - (double)r1[tid - 1];
        sd2[tid] = (double)r2[tid + 879] - (double)r2[tid - 1];
    }
    __syncthreads();

    if (tid == 0) {
        const double base1 = redb[0][0] + redb[1][0] + redb[2][0] + redb[3][0];
        const double base2 = redb[0][1] + redb[1][1] + redb[2][1] + redb[3][1];
        const double sum_t = redb[0][2] + redb[1][2] + redb[2][2] + redb[3][2];
        const double sum_t2 = redb[0][3] + redb[1][3] + redb[2][3] + redb[3][3];
        const double sumX = redb[0][4] + redb[1][4] + redb[2][4] + redb[3][4];
        const double NT = 774400.0;
        const double mt = sum_t / NT, mx = sumX / 810000.0;
        const double tvar = sum_t2 - sum_t * sum_t / NT + EPSV;
        double w1 = base1, w2 = base2;
        for (int i = 0; i < SS; ++i) {
            if (i) { w1 += sd1[i]; w2 += sd2[i]; }
            double var = w2 - w1 * w1 / NT + EPSV;
            if (var < 0.0) var = 0.0;
            const double cross = sdot[i] - mt * w1 - mx * sum_t + NT * mx * mt;
            float v = (float)(cross / sqrt(tvar * var));
            if (isnan(v)) v = 0.f;
            ncc[i * SS + j] = v;
        }
    }
}

// ---------------- shift with fused argmax+subpixel (redundant per block) ----------
__global__ __launch_bounds__(256) void shift_kernel(const float* __restrict__ img,
                                                    const float* __restrict__ ncc,
                                                    float* __restrict__ out) {
    __shared__ float sv[256];
    __shared__ int si[256];
    __shared__ float sxy[2];
    __shared__ float tile[64][65];
    const int tid = threadIdx.x;

    // argmax over 441 (first-occurrence tie-break)
    {
        float v = -1e30f; int vi = 0;
        for (int k = tid; k < SS * SS; k += 256) {
            float q = ncc[k];
            if (q > v) { v = q; vi = k; }
        }
        sv[tid] = v; si[tid] = vi;
        __syncthreads();
        for (int off = 128; off > 0; off >>= 1) {
            if (tid < off) {
                float v2 = sv[tid + off]; int i2 = si[tid + off];
                if (v2 > sv[tid] || (v2 == sv[tid] && i2 < si[tid])) { sv[tid] = v2; si[tid] = i2; }
            }
            __syncthreads();
        }
        if (tid == 0) {
            int idx = si[0];
            int sx = idx / SS;
            int sy = idx - sx * SS;
            auto at = [&](int r, int c) -> float {
                r = r < 0 ? 0 : (r > SS - 1 ? SS - 1 : r);
                c = c < 0 ? 0 : (c > SS - 1 ? SS - 1 : c);
                return logf(ncc[r * SS + c]);
            };
            float l4 = 4.0f * at(sx, sy);
            float lxm = at(sx - 1, sy), lxp = at(sx + 1, sy);
            float lym = at(sx, sy - 1), lyp = at(sx, sy + 1);
            float xsv = -((float)sx - (float)MS) - (lxm - lxp) / (2.0f * lxm - l4 + 2.0f * lxp);
            float ysv = -((float)sy - (float)MS) - (lym - lyp) / (2.0f * lym - l4 + 2.0f * lyp);
            sxy[0] = xsv; sxy[1] = ysv;
            if (blockIdx.x == 0 && blockIdx.y == 0) {
                out[(size_t)HH * WW] = xsv;
                out[(size_t)HH * WW + 1] = ysv;
            }
        }
        __syncthreads();
    }

    const float xs = sxy[0], ys = sxy[1];
    const int R0 = blockIdx.y * 64, C0 = blockIdx.x * 64;
    {
        const int cl = tid & 63, rg = tid >> 6;
        const int c = C0 + cl;
        const float cc = (float)c - ys;
        const float c0f = floorf(cc);
        const float wc = cc - c0f;
        const int c0 = (int)c0f;
        const bool vc0 = (c0 >= 0) & (c0 < WW);
        const bool vc1 = (c0 + 1 >= 0) & (c0 + 1 < WW);
        const int c0c = c0 < 0 ? 0 : (c0 > WW - 1 ? WW - 1 : c0);
        const int c1c = (c0 + 1) < 0 ? 0 : ((c0 + 1) > WW - 1 ? WW - 1 : c0 + 1);
        for (int k = 0; k < 16; ++k) {
            const int rl = rg * 16 + k;
            const int r = R0 + rl;
            const float rr = (float)r - xs;
            const float r0f = floorf(rr);
            const float wr = rr - r0f;
            const int r0 = (int)r0f;
            const bool vr0 = (r0 >= 0) & (r0 < HH);
            const bool vr1 = (r0 + 1 >= 0) & (r0 + 1 < HH);
            const int r0c = r0 < 0 ? 0 : (r0 > HH - 1 ? HH - 1 : r0);
            const int r1c = (r0 + 1) < 0 ? 0 : ((r0 + 1) > HH - 1 ? HH - 1 : r0 + 1);
            float s00 = img[(size_t)r0c * WW + c0c]; if (!(vr0 & vc0)) s00 = 0.f;
            float s01 = img[(size_t)r0c * WW + c1c]; if (!(vr0 & vc1)) s01 = 0.f;
            float s10 = img[(size_t)r1c * WW + c0c]; if (!(vr1 & vc0)) s10 = 0.f;
            float s11 = img[(size_t)r1c * WW + c1c]; if (!(vr1 & vc1)) s11 = 0.f;
            tile[rl][cl] = (1.f - wr) * (1.f - wc) * s00 + (1.f - wr) * wc * s01 +
                           wr * (1.f - wc) * s10 + wr * wc * s11;
        }
    }
    __syncthreads();
    {
        const int rl = tid & 63, cg = tid >> 6;
        for (int k = 0; k < 16; ++k) {
            const int cl = cg * 16 + k;
            out[(size_t)(C0 + cl) * HH + R0 + rl] = tile[rl][cl];
        }
    }
}

extern "C" void kernel_launch(void* const* d_in, const int* in_sizes, int n_in,
                              void* d_out, int out_size, void* d_ws, size_t ws_size,
                              hipStream_t stream) {
    const float* X = (const float*)d_in[0];
    const float* T = (const float*)d_in[1];
    float* out = (float*)d_out;

    char* w = (char*)d_ws;
    float* RS1T  = (float*)(w + 0);
    float* RS2T  = (float*)(w + 75600);
    float* Trow1 = (float*)(w + 151200);
    float* Trow2 = (float*)(w + 154720);
    float* Sfull = (float*)(w + 158240);
    float* part  = (float*)(w + 161840);
    float* ncc   = (float*)(w + 258880);

    fused_corr_stats<<<NCORR + CD + TW, 256, 0, stream>>>(X, T, RS1T, RS2T, Trow1, Trow2, Sfull, part);
    ncc_scan_kernel<<<SS, 256, 0, stream>>>(part, RS1T, RS2T, Trow1, Trow2, Sfull, ncc);
    shift_kernel<<<dim3(16, 16), 256, 0, stream>>>(X, ncc, out);
}

// Round 6
// 93.704 us; speedup vs baseline: 1.3002x; 1.0660x over previous
//
#include <hip/hip_runtime.h>
#include <math.h>

#define HH 1024
#define WW 1024
#define CD 900
#define MS 10
#define CS 62            // (H-CD)/2
#define OFFT 72          // MS+CS
#define TW 880           // H-2*OFF
#define SS 21            // 2*MS+1
#define EPSV 1e-8
#define NBAND 55         // 880/16 bands of template rows
#define RPB 16           // template rows per corr block
#define NCH 55           // 880/16 column chunks of 16
#define NPAIR 441        // 21*21
#define NIG 7            // i-groups (3 lags each): 21 = 3*7
#define IPG 3            // i per group
#define AROWS 18         // RPB + IPG - 1 X-rows touched per (band, group)
#define NCORR (NBAND * NIG)  // 385 corr blocks

// ws layout (floats):
//   RS1T  : w + 0        [21*900]  window sums, transposed [j][row]
//   RS2T  : w + 75600    [21*900]
//   Trow1 : w + 151200   [880]
//   Trow2 : w + 154720   [880]
//   Sfull : w + 158240   [900]
//   part  : w + 161840   [21*55*21]
//   ncc   : w + 258880   [441]

// Finalize-stage grid-size law (measured R1/R4/R5): tiny-data reductions here are
// LATENCY-bound, not BW-bound — 1-block=+8us, 21-block=+6us, 256-redundant=+28us
// vs the 441-block redundant form. Keep finalize grids >= ~250 blocks.

// ---------------- fused: raw cross-correlation (3-i blocked) + row statistics ----
// blocks [0, 385): corr — 16 template rows vs 3 row-lags; X row loaded once, used
//   for 3 (lag, template-row) pairs -> L2 traffic /3 vs 1-i blocking.
// blocks [385, 385+1780): per-row window sums / template row sums.
__global__ __launch_bounds__(256) void fused_corr_stats(const float* __restrict__ X,
                                                        const float* __restrict__ T,
                                                        float* __restrict__ RS1T,
                                                        float* __restrict__ RS2T,
                                                        float* __restrict__ Trow1,
                                                        float* __restrict__ Trow2,
                                                        float* __restrict__ Sfull,
                                                        float* __restrict__ part) {
    const int bx = blockIdx.x;
    const int tid = threadIdx.x;
    const int lane = tid & 63, wid = tid >> 6;
    __shared__ float red[4][IPG * SS];

    if (bx < NCORR) {
        // ---- corr: block = (band of 16 template rows, group of 3 lags) ----
        const int g = bx / NBAND;
        const int band = bx - g * NBAND;
        const int i0 = g * IPG;
        const int u0 = band * RPB;

        float acc[IPG][SS];
#pragma unroll
        for (int d = 0; d < IPG; ++d)
#pragma unroll
            for (int j = 0; j < SS; ++j) acc[d][j] = 0.f;

        // item = (a, c): X row CS+i0+u0+a, 16-col chunk c.
        // For d=0..2: template row u = a-d (valid if 0<=u<16); lag i0+d.
#pragma unroll 1
        for (int item = tid; item < AROWS * NCH; item += 256) {
            const int a = item / NCH;
            const int c = item - a * NCH;
            // x cols [60+16c, 100+16c): 16B-aligned; needed cols 62+16c+j+k (j+k<=35)
            const float4* xp = (const float4*)(X + (size_t)(CS + i0 + u0 + a) * WW + 60 + c * 16);
            float xr[40];
#pragma unroll
            for (int k = 0; k < 10; ++k) {
                float4 q = xp[k];
                xr[4 * k] = q.x; xr[4 * k + 1] = q.y; xr[4 * k + 2] = q.z; xr[4 * k + 3] = q.w;
            }
#pragma unroll
            for (int d = 0; d < IPG; ++d) {
                const int u = a - d;
                if (u >= 0 && u < RPB) {
                    // t cols [72+16c, 88+16c): 16B-aligned
                    const float4* tp = (const float4*)(T + (size_t)(OFFT + u0 + u) * WW + OFFT + c * 16);
                    float t[16];
#pragma unroll
                    for (int k = 0; k < 4; ++k) {
                        float4 q = tp[k];
                        t[4 * k] = q.x; t[4 * k + 1] = q.y; t[4 * k + 2] = q.z; t[4 * k + 3] = q.w;
                    }
#pragma unroll
                    for (int j = 0; j < SS; ++j) {
                        float s = acc[d][j];
#pragma unroll
                        for (int k = 0; k < 16; ++k) s = fmaf(xr[2 + j + k], t[k], s);
                        acc[d][j] = s;
                    }
                }
            }
        }

#pragma unroll
        for (int d = 0; d < IPG; ++d)
#pragma unroll
            for (int j = 0; j < SS; ++j)
#pragma unroll
                for (int m = 1; m < 64; m <<= 1) acc[d][j] += __shfl_xor(acc[d][j], m);

        if (lane == 0) {
#pragma unroll
            for (int d = 0; d < IPG; ++d)
#pragma unroll
                for (int j = 0; j < SS; ++j) red[wid][d * SS + j] = acc[d][j];
        }
        __syncthreads();
        if (tid < IPG * SS) {
            const int d = tid / SS, j = tid - d * SS;
            float s = red[0][tid] + red[1][tid] + red[2][tid] + red[3][tid];
            part[((i0 + d) * NBAND + band) * SS + j] = s;
        }
    } else {
        // ---- row statistics part (no atomics, no memset needed) ----
        const int b = bx - NCORR;
        if (b < CD) {
            const float* row = X + (size_t)(CS + b) * WW + CS;   // 900 valid cols
            float sf = 0.f, sw = 0.f, qw = 0.f;
            for (int v = tid; v < CD; v += 256) {
                float x = row[v];
                sf += x;
                if (v < TW) { sw += x; qw += x * x; }
            }
            for (int m = 1; m < 64; m <<= 1) {
                sf += __shfl_xor(sf, m); sw += __shfl_xor(sw, m); qw += __shfl_xor(qw, m);
            }
            if (lane == 0) { red[wid][0] = sf; red[wid][1] = sw; red[wid][2] = qw; }
            __syncthreads();
            if (tid < 32) {
                const float swb = red[0][1] + red[1][1] + red[2][1] + red[3][1];
                const float qwb = red[0][2] + red[1][2] + red[2][2] + red[3][2];
                // lag-j window sum = base + prefix sum of slide deltas (parallel scan)
                float d1 = 0.f, d2 = 0.f;
                if (tid >= 1 && tid < SS) {
                    float a = row[tid - 1], c2 = row[TW + tid - 1];
                    d1 = c2 - a;
                    d2 = c2 * c2 - a * a;
                }
                for (int off = 1; off < 32; off <<= 1) {
                    float u1 = __shfl_up(d1, off), u2 = __shfl_up(d2, off);
                    if (tid >= off) { d1 += u1; d2 += u2; }
                }
                if (tid < SS) {
                    RS1T[tid * CD + b] = swb + d1;
                    RS2T[tid * CD + b] = qwb + d2;
                }
                if (tid == 0) Sfull[b] = red[0][0] + red[1][0] + red[2][0] + red[3][0];
            }
        } else {
            const int u = b - CD;
            const float* row = T + (size_t)(OFFT + u) * WW + OFFT;
            float s = 0.f, q = 0.f;
            for (int v = tid; v < TW; v += 256) { float t = row[v]; s += t; q += t * t; }
            for (int m = 1; m < 64; m <<= 1) { s += __shfl_xor(s, m); q += __shfl_xor(q, m); }
            if (lane == 0) { red[wid][0] = s; red[wid][1] = q; }
            __syncthreads();
            if (tid == 0) {
                Trow1[u] = red[0][0] + red[1][0] + red[2][0] + red[3][0];
                Trow2[u] = red[0][1] + red[1][1] + red[2][1] + red[3][1];
            }
        }
    }
}

// ---------------- combine -> ncc (computes global sums redundantly per block) -----
__global__ __launch_bounds__(256) void ncc_final_kernel(const float* __restrict__ part,
                                                        const float* __restrict__ RS1T,
                                                        const float* __restrict__ RS2T,
                                                        const float* __restrict__ Trow1,
                                                        const float* __restrict__ Trow2,
                                                        const float* __restrict__ Sfull,
                                                        float* __restrict__ ncc) {
    const int bid = blockIdx.x;
    const int i = bid / SS, j = bid - i * SS;
    const int tid = threadIdx.x;
    double dd = 0, d1 = 0, d2 = 0, ta = 0, tb = 0, xs = 0;
    for (int b = tid; b < NBAND; b += 256) dd += (double)part[(i * NBAND + b) * SS + j];
    const float* r1 = RS1T + j * CD + i;   // contiguous
    const float* r2 = RS2T + j * CD + i;
    for (int u = tid; u < TW; u += 256) {
        d1 += (double)r1[u]; d2 += (double)r2[u];
        ta += (double)Trow1[u]; tb += (double)Trow2[u];
    }
    for (int k = tid; k < CD; k += 256) xs += (double)Sfull[k];
    for (int m = 1; m < 64; m <<= 1) {
        dd += __shfl_xor(dd, m); d1 += __shfl_xor(d1, m); d2 += __shfl_xor(d2, m);
        ta += __shfl_xor(ta, m); tb += __shfl_xor(tb, m); xs += __shfl_xor(xs, m);
    }
    __shared__ double red[4][6];
    const int lane = tid & 63, wid = tid >> 6;
    if (lane == 0) {
        red[wid][0] = dd; red[wid][1] = d1; red[wid][2] = d2;
        red[wid][3] = ta; red[wid][4] = tb; red[wid][5] = xs;
    }
    __syncthreads();
    if (tid == 0) {
        double dot = red[0][0] + red[1][0] + red[2][0] + red[3][0];
        double S1  = red[0][1] + red[1][1] + red[2][1] + red[3][1];
        double S2  = red[0][2] + red[1][2] + red[2][2] + red[3][2];
        double sum_t  = red[0][3] + red[1][3] + red[2][3] + red[3][3];
        double sum_t2 = red[0][4] + red[1][4] + red[2][4] + red[3][4];
        double sumX   = red[0][5] + red[1][5] + red[2][5] + red[3][5];
        const double NT = 774400.0;
        double mt = sum_t / NT, mx = sumX / 810000.0;
        double tvar = sum_t2 - sum_t * sum_t / NT + EPSV;
        double var = S2 - S1 * S1 / NT + EPSV;
        if (var < 0.0) var = 0.0;
        double cross = dot - mt * S1 - mx * sum_t + NT * mx * mt;
        float val = (float)(cross / sqrt(tvar * var));
        if (isnan(val)) val = 0.f;
        ncc[i * SS + j] = val;
    }
}

// ---------------- shift with fused argmax+subpixel (redundant per block) ----------
__global__ __launch_bounds__(256) void shift_kernel(const float* __restrict__ img,
                                                    const float* __restrict__ ncc,
                                                    float* __restrict__ out) {
    __shared__ float sv[256];
    __shared__ int si[256];
    __shared__ float sxy[2];
    __shared__ float tile[64][65];
    const int tid = threadIdx.x;

    // argmax over 441 (first-occurrence tie-break)
    {
        float v = -1e30f; int vi = 0;
        for (int k = tid; k < SS * SS; k += 256) {
            float q = ncc[k];
            if (q > v) { v = q; vi = k; }
        }
        sv[tid] = v; si[tid] = vi;
        __syncthreads();
        for (int off = 128; off > 0; off >>= 1) {
            if (tid < off) {
                float v2 = sv[tid + off]; int i2 = si[tid + off];
                if (v2 > sv[tid] || (v2 == sv[tid] && i2 < si[tid])) { sv[tid] = v2; si[tid] = i2; }
            }
            __syncthreads();
        }
        if (tid == 0) {
            int idx = si[0];
            int sx = idx / SS;
            int sy = idx - sx * SS;
            auto at = [&](int r, int c) -> float {
                r = r < 0 ? 0 : (r > SS - 1 ? SS - 1 : r);
                c = c < 0 ? 0 : (c > SS - 1 ? SS - 1 : c);
                return logf(ncc[r * SS + c]);
            };
            float l4 = 4.0f * at(sx, sy);
            float lxm = at(sx - 1, sy), lxp = at(sx + 1, sy);
            float lym = at(sx, sy - 1), lyp = at(sx, sy + 1);
            float xsv = -((float)sx - (float)MS) - (lxm - lxp) / (2.0f * lxm - l4 + 2.0f * lxp);
            float ysv = -((float)sy - (float)MS) - (lym - lyp) / (2.0f * lym - l4 + 2.0f * lyp);
            sxy[0] = xsv; sxy[1] = ysv;
            if (blockIdx.x == 0 && blockIdx.y == 0) {
                out[(size_t)HH * WW] = xsv;
                out[(size_t)HH * WW + 1] = ysv;
            }
        }
        __syncthreads();
    }

    const float xs = sxy[0], ys = sxy[1];
    const int R0 = blockIdx.y * 64, C0 = blockIdx.x * 64;
    {
        const int cl = tid & 63, rg = tid >> 6;
        const int c = C0 + cl;
        const float cc = (float)c - ys;
        const float c0f = floorf(cc);
        const float wc = cc - c0f;
        const int c0 = (int)c0f;
        const bool vc0 = (c0 >= 0) & (c0 < WW);
        const bool vc1 = (c0 + 1 >= 0) & (c0 + 1 < WW);
        const int c0c = c0 < 0 ? 0 : (c0 > WW - 1 ? WW - 1 : c0);
        const int c1c = (c0 + 1) < 0 ? 0 : ((c0 + 1) > WW - 1 ? WW - 1 : c0 + 1);
        for (int k = 0; k < 16; ++k) {
            const int rl = rg * 16 + k;
            const int r = R0 + rl;
            const float rr = (float)r - xs;
            const float r0f = floorf(rr);
            const float wr = rr - r0f;
            const int r0 = (int)r0f;
            const bool vr0 = (r0 >= 0) & (r0 < HH);
            const bool vr1 = (r0 + 1 >= 0) & (r0 + 1 < HH);
            const int r0c = r0 < 0 ? 0 : (r0 > HH - 1 ? HH - 1 : r0);
            const int r1c = (r0 + 1) < 0 ? 0 : ((r0 + 1) > HH - 1 ? HH - 1 : r0 + 1);
            float s00 = img[(size_t)r0c * WW + c0c]; if (!(vr0 & vc0)) s00 = 0.f;
            float s01 = img[(size_t)r0c * WW + c1c]; if (!(vr0 & vc1)) s01 = 0.f;
            float s10 = img[(size_t)r1c * WW + c0c]; if (!(vr1 & vc0)) s10 = 0.f;
            float s11 = img[(size_t)r1c * WW + c1c]; if (!(vr1 & vc1)) s11 = 0.f;
            tile[rl][cl] = (1.f - wr) * (1.f - wc) * s00 + (1.f - wr) * wc * s01 +
                           wr * (1.f - wc) * s10 + wr * wc * s11;
        }
    }
    __syncthreads();
    {
        const int rl = tid & 63, cg = tid >> 6;
        for (int k = 0; k < 16; ++k) {
            const int cl = cg * 16 + k;
            out[(size_t)(C0 + cl) * HH + R0 + rl] = tile[rl][cl];
        }
    }
}

extern "C" void kernel_launch(void* const* d_in, const int* in_sizes, int n_in,
                              void* d_out, int out_size, void* d_ws, size_t ws_size,
                              hipStream_t stream) {
    const float* X = (const float*)d_in[0];
    const float* T = (const float*)d_in[1];
    float* out = (float*)d_out;

    char* w = (char*)d_ws;
    float* RS1T  = (float*)(w + 0);
    float* RS2T  = (float*)(w + 75600);
    float* Trow1 = (float*)(w + 151200);
    float* Trow2 = (float*)(w + 154720);
    float* Sfull = (float*)(w + 158240);
    float* part  = (float*)(w + 161840);
    float* ncc   = (float*)(w + 258880);

    fused_corr_stats<<<NCORR + CD + TW, 256, 0, stream>>>(X, T, RS1T, RS2T, Trow1, Trow2, Sfull, part);
    ncc_final_kernel<<<SS * SS, 256, 0, stream>>>(part, RS1T, RS2T, Trow1, Trow2, Sfull, ncc);
    shift_kernel<<<dim3(16, 16), 256, 0, stream>>>(X, ncc, out);
}